// Round 4
// baseline (33.247 us; speedup 1.0000x reference)
//
#include <hip/hip_runtime.h>

// EntropyBottleneck fused likelihood + quantize, paired-table version.
// likelihood(y) depends only on y = x/s_c (58 shared params):
//   kernel 1 tabulates pairs (F(y_i), F(y_i + h)) at NT points over [-16,16];
//   kernel 2 (memory-bound): q = fmaf(x, inv*sc, noise*sc),
//            lik = lerp of one ds_read_b64 pair. No final clamp needed:
//            table entries are >= 1e-9 and lerp is a convex combination.

#define NT   2048
#define TLO  (-16.0f)
#define THI  ( 16.0f)

__device__ __forceinline__ float frcp(float x) { return __builtin_amdgcn_rcpf(x); }

__device__ __forceinline__ float ftanh(float x) {
    float e = __expf(2.0f * x);
    return 1.0f - 2.0f * frcp(e + 1.0f);
}

__device__ __forceinline__ float fsigm(float x) {
    return frcp(1.0f + __expf(-x));
}

__device__ __forceinline__ float fsoftplus(float x) {
    return __logf(1.0f + __expf(x));
}

struct EBP {
    float m0[3], b0[3], t0[3];
    float m1[9], b1[3], t1[3];
    float m2[9], b2[3], t2[3];
    float m3[9], b3[3], t3[3];
    float m4[3], b4;
    float sc, inv;
};

__device__ __forceinline__ void load_params(
    EBP& p,
    const float* s,
    const float* m0_, const float* b0_, const float* f0_,
    const float* m1_, const float* b1_, const float* f1_,
    const float* m2_, const float* b2_, const float* f2_,
    const float* m3_, const float* b3_, const float* f3_,
    const float* m4_, const float* b4_)
{
#pragma unroll
    for (int i = 0; i < 3; i++) { p.m0[i] = fsoftplus(m0_[i]); p.b0[i] = b0_[i]; p.t0[i] = ftanh(f0_[i]); }
#pragma unroll
    for (int i = 0; i < 9; i++) p.m1[i] = fsoftplus(m1_[i]);
#pragma unroll
    for (int i = 0; i < 3; i++) { p.b1[i] = b1_[i]; p.t1[i] = ftanh(f1_[i]); }
#pragma unroll
    for (int i = 0; i < 9; i++) p.m2[i] = fsoftplus(m2_[i]);
#pragma unroll
    for (int i = 0; i < 3; i++) { p.b2[i] = b2_[i]; p.t2[i] = ftanh(f2_[i]); }
#pragma unroll
    for (int i = 0; i < 9; i++) p.m3[i] = fsoftplus(m3_[i]);
#pragma unroll
    for (int i = 0; i < 3; i++) { p.b3[i] = b3_[i]; p.t3[i] = ftanh(f3_[i]); }
#pragma unroll
    for (int i = 0; i < 3; i++) p.m4[i] = fsoftplus(m4_[i]);
    p.b4 = b4_[0];
    p.sc = fmaxf(s[0], 1e-4f);
    p.inv = 1.0f / p.sc;
}

__device__ __forceinline__ float logits_cum(const EBP& p, float v) {
    float h[3], g[3];
#pragma unroll
    for (int o = 0; o < 3; o++) {
        float l = fmaf(p.m0[o], v, p.b0[o]);
        h[o] = fmaf(p.t0[o], ftanh(l), l);
    }
#pragma unroll
    for (int o = 0; o < 3; o++) {
        float l = p.b1[o];
#pragma unroll
        for (int i = 0; i < 3; i++) l = fmaf(p.m1[o * 3 + i], h[i], l);
        g[o] = fmaf(p.t1[o], ftanh(l), l);
    }
#pragma unroll
    for (int o = 0; o < 3; o++) {
        float l = p.b2[o];
#pragma unroll
        for (int i = 0; i < 3; i++) l = fmaf(p.m2[o * 3 + i], g[i], l);
        h[o] = fmaf(p.t2[o], ftanh(l), l);
    }
#pragma unroll
    for (int o = 0; o < 3; o++) {
        float l = p.b3[o];
#pragma unroll
        for (int i = 0; i < 3; i++) l = fmaf(p.m3[o * 3 + i], h[i], l);
        g[o] = fmaf(p.t3[o], ftanh(l), l);
    }
    float out = p.b4;
#pragma unroll
    for (int i = 0; i < 3; i++) out = fmaf(p.m4[i], g[i], out);
    return out;
}

__device__ __forceinline__ float eb_lik(const EBP& p, float y) {
    float l = logits_cum(p, y - 0.5f);
    float u = logits_cum(p, y + 0.5f);
    float sum = l + u;
    float sg = (sum > 0.0f) ? -1.0f : ((sum < 0.0f) ? 1.0f : 0.0f);
    float a = fsigm(sg * u);
    float b = fsigm(sg * l);
    return fmaxf(fabsf(a - b), 1e-9f);
}

// ---- kernel 1: tabulate pairs (F(y_i), F(y_i+h)) into d_ws ----
__global__ __launch_bounds__(256) void eb_build_table(
    const float* __restrict__ s,
    const float* __restrict__ m0_, const float* __restrict__ b0_, const float* __restrict__ f0_,
    const float* __restrict__ m1_, const float* __restrict__ b1_, const float* __restrict__ f1_,
    const float* __restrict__ m2_, const float* __restrict__ b2_, const float* __restrict__ f2_,
    const float* __restrict__ m3_, const float* __restrict__ b3_, const float* __restrict__ f3_,
    const float* __restrict__ m4_, const float* __restrict__ b4_,
    float2* __restrict__ table)
{
    int idx = blockIdx.x * blockDim.x + threadIdx.x;
    if (idx >= NT) return;
    EBP p;
    load_params(p, s, m0_, b0_, f0_, m1_, b1_, f1_, m2_, b2_, f2_, m3_, b3_, f3_, m4_, b4_);
    const float hstep = (THI - TLO) / (float)(NT - 1);
    float y = TLO + (float)idx * hstep;
    float2 v;
    v.x = eb_lik(p, y);
    v.y = eb_lik(p, y + hstep);
    table[idx] = v;
}

// ---- kernel 2: memory-bound main pass ----
__global__ __launch_bounds__(256) void eb_main(
    const float* __restrict__ x, const float* __restrict__ nz,
    const float* __restrict__ s, const float2* __restrict__ table,
    float* __restrict__ out, int n)
{
    __shared__ float2 tab[NT];
    {
        float4* t4 = (float4*)tab;
        const float4* g4 = (const float4*)table;
        for (int i = threadIdx.x; i < NT / 2; i += blockDim.x) t4[i] = g4[i];
    }
    __syncthreads();

    const float sc  = fmaxf(s[0], 1e-4f);
    const float inv = 1.0f / sc;
    const float invh = (float)(NT - 1) / (THI - TLO);
    const float qa = inv * sc;            // q = fmaf(x, qa, ns*sc)
    const float ta = inv * invh;          // t = fmaf(x, ta, tb)
    const float tb = -TLO * invh;
    const float tmax = (float)(NT - 1) - 1e-3f;  // floor() <= NT-2

    float* __restrict__ oq = out;
    float* __restrict__ ol = out + n;

    const int nvec = n >> 2;
    const int stride = gridDim.x * blockDim.x;
    const float4* __restrict__ x4 = (const float4*)x;
    const float4* __restrict__ n4 = (const float4*)nz;

    for (int i = blockIdx.x * blockDim.x + threadIdx.x; i < nvec; i += stride) {
        float4 xv = x4[i];
        float4 nv = n4[i];
        float4 qv, lv;
        const float* xs = (const float*)&xv;
        const float* ns = (const float*)&nv;
        float* qs = (float*)&qv;
        float* ls = (float*)&lv;
#pragma unroll
        for (int j = 0; j < 4; j++) {
            qs[j] = fmaf(xs[j], qa, ns[j] * sc);
            float t = fmaf(xs[j], ta, tb);
            t = fminf(fmaxf(t, 0.0f), tmax);
            float fi = floorf(t);
            float frac = t - fi;
            float2 ff = tab[(int)fi];            // one ds_read_b64
            ls[j] = fmaf(frac, ff.y - ff.x, ff.x);  // >= 1e-9 by construction
        }
        ((float4*)oq)[i] = qv;
        ((float4*)ol)[i] = lv;
    }

    const int rem = n & 3;
    if (rem) {
        const int base = nvec << 2;
        const int t0 = blockIdx.x * blockDim.x + threadIdx.x;
        if (t0 < rem) {
            const int idx = base + t0;
            float xv = x[idx];
            oq[idx] = fmaf(xv, qa, nz[idx] * sc);
            float t = fmaf(xv, ta, tb);
            t = fminf(fmaxf(t, 0.0f), tmax);
            float fi = floorf(t);
            float2 ff = tab[(int)fi];
            ol[idx] = fmaf(t - fi, ff.y - ff.x, ff.x);
        }
    }
}

// ---- fallback: direct per-element evaluation (if ws too small) ----
__global__ __launch_bounds__(256) void eb_direct(
    const float* __restrict__ x, const float* __restrict__ nz,
    const float* __restrict__ s,
    const float* __restrict__ m0_, const float* __restrict__ b0_, const float* __restrict__ f0_,
    const float* __restrict__ m1_, const float* __restrict__ b1_, const float* __restrict__ f1_,
    const float* __restrict__ m2_, const float* __restrict__ b2_, const float* __restrict__ f2_,
    const float* __restrict__ m3_, const float* __restrict__ b3_, const float* __restrict__ f3_,
    const float* __restrict__ m4_, const float* __restrict__ b4_,
    float* __restrict__ out, int n)
{
    EBP p;
    load_params(p, s, m0_, b0_, f0_, m1_, b1_, f1_, m2_, b2_, f2_, m3_, b3_, f3_, m4_, b4_);
    float* __restrict__ oq = out;
    float* __restrict__ ol = out + n;
    const int stride = gridDim.x * blockDim.x;
    for (int i = blockIdx.x * blockDim.x + threadIdx.x; i < n; i += stride) {
        float y = x[i] * p.inv;
        oq[i] = (y + nz[i]) * p.sc;
        ol[i] = eb_lik(p, y);
    }
}

extern "C" void kernel_launch(void* const* d_in, const int* in_sizes, int n_in,
                              void* d_out, int out_size, void* d_ws, size_t ws_size,
                              hipStream_t stream) {
    const float* x  = (const float*)d_in[0];
    const float* nz = (const float*)d_in[1];
    const float* s  = (const float*)d_in[2];
    const float* m0 = (const float*)d_in[3];
    const float* b0 = (const float*)d_in[4];
    const float* f0 = (const float*)d_in[5];
    const float* m1 = (const float*)d_in[6];
    const float* b1 = (const float*)d_in[7];
    const float* f1 = (const float*)d_in[8];
    const float* m2 = (const float*)d_in[9];
    const float* b2 = (const float*)d_in[10];
    const float* f2 = (const float*)d_in[11];
    const float* m3 = (const float*)d_in[12];
    const float* b3 = (const float*)d_in[13];
    const float* f3 = (const float*)d_in[14];
    const float* m4 = (const float*)d_in[15];
    const float* b4 = (const float*)d_in[16];
    const int n = in_sizes[0];

    if (ws_size >= (size_t)(NT * sizeof(float2))) {
        float2* table = (float2*)d_ws;
        eb_build_table<<<NT / 256, 256, 0, stream>>>(
            s, m0, b0, f0, m1, b1, f1, m2, b2, f2, m3, b3, f3, m4, b4, table);
        eb_main<<<2048, 256, 0, stream>>>(x, nz, s, table, (float*)d_out, n);
    } else {
        eb_direct<<<2048, 256, 0, stream>>>(
            x, nz, s, m0, b0, f0, m1, b1, f1, m2, b2, f2, m3, b3, f3, m4, b4,
            (float*)d_out, n);
    }
}

// Round 6
// 32.035 us; speedup vs baseline: 1.0378x; 1.0378x over previous
//
#include <hip/hip_runtime.h>

// EntropyBottleneck fused likelihood + quantize — single-kernel, per-block LDS table.
// likelihood(y) depends only on y = x/s_c (58 shared params). Each block:
//   phase 0: lanes 0..58 transform params into LDS (softplus/tanh once)
//   phase 1: 256 lanes tabulate F(y_i) over [-16,16] into LDS (1 eval/lane)
//   phase 2: memory-bound stream: q = fmaf(x, inv*sc, noise*sc), lik = lerp(tab)
// F is ultra-smooth (composed logit slope ~1e-5; NT=4096 and NT=2048 both gave
// absmax bit-identical to direct eval), so NT=256 lerp error ~1e-7 << threshold.

#define NT   256
#define TLO  (-16.0f)
#define THI  ( 16.0f)

typedef float v4f __attribute__((ext_vector_type(4)));  // clang vector: OK for nontemporal builtins

__device__ __forceinline__ float frcp(float x) { return __builtin_amdgcn_rcpf(x); }

__device__ __forceinline__ float ftanh(float x) {
    float e = __expf(2.0f * x);
    return 1.0f - 2.0f * frcp(e + 1.0f);
}

__device__ __forceinline__ float fsigm(float x) {
    return frcp(1.0f + __expf(-x));
}

__device__ __forceinline__ float fsoftplus(float x) {
    return __logf(1.0f + __expf(x));
}

struct EBP {
    float m0[3], b0[3], t0[3];
    float m1[9], b1[3], t1[3];
    float m2[9], b2[3], t2[3];
    float m3[9], b3[3], t3[3];
    float m4[3], b4;
};

__device__ __forceinline__ float logits_cum(const EBP& p, float v) {
    float h[3], g[3];
#pragma unroll
    for (int o = 0; o < 3; o++) {
        float l = fmaf(p.m0[o], v, p.b0[o]);
        h[o] = fmaf(p.t0[o], ftanh(l), l);
    }
#pragma unroll
    for (int o = 0; o < 3; o++) {
        float l = p.b1[o];
#pragma unroll
        for (int i = 0; i < 3; i++) l = fmaf(p.m1[o * 3 + i], h[i], l);
        g[o] = fmaf(p.t1[o], ftanh(l), l);
    }
#pragma unroll
    for (int o = 0; o < 3; o++) {
        float l = p.b2[o];
#pragma unroll
        for (int i = 0; i < 3; i++) l = fmaf(p.m2[o * 3 + i], g[i], l);
        h[o] = fmaf(p.t2[o], ftanh(l), l);
    }
#pragma unroll
    for (int o = 0; o < 3; o++) {
        float l = p.b3[o];
#pragma unroll
        for (int i = 0; i < 3; i++) l = fmaf(p.m3[o * 3 + i], h[i], l);
        g[o] = fmaf(p.t3[o], ftanh(l), l);
    }
    float out = p.b4;
#pragma unroll
    for (int i = 0; i < 3; i++) out = fmaf(p.m4[i], g[i], out);
    return out;
}

__device__ __forceinline__ float eb_lik(const EBP& p, float y) {
    float l = logits_cum(p, y - 0.5f);
    float u = logits_cum(p, y + 0.5f);
    float sum = l + u;
    float sg = (sum > 0.0f) ? -1.0f : ((sum < 0.0f) ? 1.0f : 0.0f);
    float a = fsigm(sg * u);
    float b = fsigm(sg * l);
    return fmaxf(fabsf(a - b), 1e-9f);
}

// LDS param map: [0..32]=softplus(m), [33..44]=tanh(f), [45..57]=b, 58=sc, 59=inv
__global__ __launch_bounds__(256, 4) void eb_fused(
    const float* __restrict__ x, const float* __restrict__ nz,
    const float* __restrict__ s,
    const float* __restrict__ m0_, const float* __restrict__ b0_, const float* __restrict__ f0_,
    const float* __restrict__ m1_, const float* __restrict__ b1_, const float* __restrict__ f1_,
    const float* __restrict__ m2_, const float* __restrict__ b2_, const float* __restrict__ f2_,
    const float* __restrict__ m3_, const float* __restrict__ b3_, const float* __restrict__ f3_,
    const float* __restrict__ m4_, const float* __restrict__ b4_,
    float* __restrict__ out, int n)
{
    __shared__ float P[64];
    __shared__ float tab[NT];

    const int t = threadIdx.x;

    // ---- phase 0: parameter transform (one scalar per lane) ----
    if (t < 33) {
        const float* src = (t < 3)  ? (m0_ + t)
                         : (t < 12) ? (m1_ + (t - 3))
                         : (t < 21) ? (m2_ + (t - 12))
                         : (t < 30) ? (m3_ + (t - 21))
                                    : (m4_ + (t - 30));
        P[t] = fsoftplus(*src);
    } else if (t < 45) {
        const int k = t - 33;
        const float* src = (k < 3) ? (f0_ + k)
                         : (k < 6) ? (f1_ + (k - 3))
                         : (k < 9) ? (f2_ + (k - 6))
                                   : (f3_ + (k - 9));
        P[t] = ftanh(*src);
    } else if (t < 58) {
        const int k = t - 45;
        const float* src = (k < 3)  ? (b0_ + k)
                         : (k < 6)  ? (b1_ + (k - 3))
                         : (k < 9)  ? (b2_ + (k - 6))
                         : (k < 12) ? (b3_ + (k - 9))
                                    : b4_;
        P[t] = *src;
    } else if (t == 58) {
        float sc = fmaxf(s[0], 1e-4f);
        P[58] = sc;
        P[59] = 1.0f / sc;
    }
    __syncthreads();

    // ---- phase 1: tabulate F at this lane's node ----
    {
        EBP p;
#pragma unroll
        for (int i = 0; i < 3; i++) p.m0[i] = P[i];
#pragma unroll
        for (int i = 0; i < 9; i++) p.m1[i] = P[3 + i];
#pragma unroll
        for (int i = 0; i < 9; i++) p.m2[i] = P[12 + i];
#pragma unroll
        for (int i = 0; i < 9; i++) p.m3[i] = P[21 + i];
#pragma unroll
        for (int i = 0; i < 3; i++) p.m4[i] = P[30 + i];
#pragma unroll
        for (int i = 0; i < 3; i++) { p.t0[i] = P[33 + i]; p.t1[i] = P[36 + i]; p.t2[i] = P[39 + i]; p.t3[i] = P[42 + i]; }
#pragma unroll
        for (int i = 0; i < 3; i++) { p.b0[i] = P[45 + i]; p.b1[i] = P[48 + i]; p.b2[i] = P[51 + i]; p.b3[i] = P[54 + i]; }
        p.b4 = P[57];

        const float hstep = (THI - TLO) / (float)(NT - 1);
        tab[t] = eb_lik(p, TLO + (float)t * hstep);
    }
    __syncthreads();

    // ---- phase 2: memory-bound streaming pass (8 elems/thread/iter) ----
    const float sc   = P[58];
    const float inv  = P[59];
    const float invh = (float)(NT - 1) / (THI - TLO);
    const float qa   = inv * sc;
    const float ta   = inv * invh;
    const float tb   = -TLO * invh;
    const float tmax = (float)(NT - 1) - 1e-3f;   // floor() <= NT-2

    float* __restrict__ oq = out;
    float* __restrict__ ol = out + n;

    const int nch = n >> 3;                        // chunks of 8
    const int gid = blockIdx.x * blockDim.x + threadIdx.x;
    const int stride = gridDim.x * blockDim.x;
    const v4f* __restrict__ x4 = (const v4f*)x;
    const v4f* __restrict__ n4 = (const v4f*)nz;
    v4f* __restrict__ oq4 = (v4f*)oq;
    v4f* __restrict__ ol4 = (v4f*)ol;

    for (int i = gid; i < nch; i += stride) {
        v4f xa = x4[2 * i];
        v4f xb = x4[2 * i + 1];
        v4f na = n4[2 * i];
        v4f nb = n4[2 * i + 1];
        v4f qa4, qb4, la4, lb4;
#pragma unroll
        for (int j = 0; j < 4; j++) {
            qa4[j] = fmaf(xa[j], qa, na[j] * sc);
            float tt = fmaf(xa[j], ta, tb);
            tt = fminf(fmaxf(tt, 0.0f), tmax);
            float fi = floorf(tt);
            int ii = (int)fi;
            float f0 = tab[ii];
            float f1 = tab[ii + 1];
            la4[j] = fmaf(tt - fi, f1 - f0, f0);
        }
#pragma unroll
        for (int j = 0; j < 4; j++) {
            qb4[j] = fmaf(xb[j], qa, nb[j] * sc);
            float tt = fmaf(xb[j], ta, tb);
            tt = fminf(fmaxf(tt, 0.0f), tmax);
            float fi = floorf(tt);
            int ii = (int)fi;
            float f0 = tab[ii];
            float f1 = tab[ii + 1];
            lb4[j] = fmaf(tt - fi, f1 - f0, f0);
        }
        __builtin_nontemporal_store(qa4, &oq4[2 * i]);
        __builtin_nontemporal_store(qb4, &oq4[2 * i + 1]);
        __builtin_nontemporal_store(la4, &ol4[2 * i]);
        __builtin_nontemporal_store(lb4, &ol4[2 * i + 1]);
    }

    // tail (n not divisible by 8) — not hit for N=8388608
    const int rem = n & 7;
    if (rem) {
        const int base = n - rem;
        if (gid < rem) {
            const int idx = base + gid;
            float xv = x[idx];
            oq[idx] = fmaf(xv, qa, nz[idx] * sc);
            float tt = fmaf(xv, ta, tb);
            tt = fminf(fmaxf(tt, 0.0f), tmax);
            float fi = floorf(tt);
            int ii = (int)fi;
            float f0 = tab[ii];
            float f1 = tab[ii + 1];
            ol[idx] = fmaf(tt - fi, f1 - f0, f0);
        }
    }
}

extern "C" void kernel_launch(void* const* d_in, const int* in_sizes, int n_in,
                              void* d_out, int out_size, void* d_ws, size_t ws_size,
                              hipStream_t stream) {
    const float* x  = (const float*)d_in[0];
    const float* nz = (const float*)d_in[1];
    const float* s  = (const float*)d_in[2];
    const float* m0 = (const float*)d_in[3];
    const float* b0 = (const float*)d_in[4];
    const float* f0 = (const float*)d_in[5];
    const float* m1 = (const float*)d_in[6];
    const float* b1 = (const float*)d_in[7];
    const float* f1 = (const float*)d_in[8];
    const float* m2 = (const float*)d_in[9];
    const float* b2 = (const float*)d_in[10];
    const float* f2 = (const float*)d_in[11];
    const float* m3 = (const float*)d_in[12];
    const float* b3 = (const float*)d_in[13];
    const float* f3 = (const float*)d_in[14];
    const float* m4 = (const float*)d_in[15];
    const float* b4 = (const float*)d_in[16];
    const int n = in_sizes[0];

    // 1024 blocks x 256: 4 blocks/CU resident, prologue runs once, 4 main iters.
    eb_fused<<<1024, 256, 0, stream>>>(x, nz, s,
                                       m0, b0, f0, m1, b1, f1,
                                       m2, b2, f2, m3, b3, f3,
                                       m4, b4,
                                       (float*)d_out, n);
}

// Round 7
// 31.692 us; speedup vs baseline: 1.0491x; 1.0108x over previous
//
#include <hip/hip_runtime.h>

// EntropyBottleneck fused likelihood + quantize — single-kernel, per-block LDS table.
// Round-7: plain stores (L3 absorbs the 64MB output stream; 128MB working set
// fits the 256MB L3), 2048 blocks, blocked one-shot layout: thread gid handles
// float4 indices {gid + k*T, k=0..3} so all 8 input loads issue up front and
// every load/store instruction is lane-consecutive (perfectly coalesced).

#define NT   256
#define TLO  (-16.0f)
#define THI  ( 16.0f)

typedef float v4f __attribute__((ext_vector_type(4)));

__device__ __forceinline__ float frcp(float x) { return __builtin_amdgcn_rcpf(x); }

__device__ __forceinline__ float ftanh(float x) {
    float e = __expf(2.0f * x);
    return 1.0f - 2.0f * frcp(e + 1.0f);
}

__device__ __forceinline__ float fsigm(float x) {
    return frcp(1.0f + __expf(-x));
}

__device__ __forceinline__ float fsoftplus(float x) {
    return __logf(1.0f + __expf(x));
}

struct EBP {
    float m0[3], b0[3], t0[3];
    float m1[9], b1[3], t1[3];
    float m2[9], b2[3], t2[3];
    float m3[9], b3[3], t3[3];
    float m4[3], b4;
};

__device__ __forceinline__ float logits_cum(const EBP& p, float v) {
    float h[3], g[3];
#pragma unroll
    for (int o = 0; o < 3; o++) {
        float l = fmaf(p.m0[o], v, p.b0[o]);
        h[o] = fmaf(p.t0[o], ftanh(l), l);
    }
#pragma unroll
    for (int o = 0; o < 3; o++) {
        float l = p.b1[o];
#pragma unroll
        for (int i = 0; i < 3; i++) l = fmaf(p.m1[o * 3 + i], h[i], l);
        g[o] = fmaf(p.t1[o], ftanh(l), l);
    }
#pragma unroll
    for (int o = 0; o < 3; o++) {
        float l = p.b2[o];
#pragma unroll
        for (int i = 0; i < 3; i++) l = fmaf(p.m2[o * 3 + i], g[i], l);
        h[o] = fmaf(p.t2[o], ftanh(l), l);
    }
#pragma unroll
    for (int o = 0; o < 3; o++) {
        float l = p.b3[o];
#pragma unroll
        for (int i = 0; i < 3; i++) l = fmaf(p.m3[o * 3 + i], h[i], l);
        g[o] = fmaf(p.t3[o], ftanh(l), l);
    }
    float out = p.b4;
#pragma unroll
    for (int i = 0; i < 3; i++) out = fmaf(p.m4[i], g[i], out);
    return out;
}

__device__ __forceinline__ float eb_lik(const EBP& p, float y) {
    float l = logits_cum(p, y - 0.5f);
    float u = logits_cum(p, y + 0.5f);
    float sum = l + u;
    float sg = (sum > 0.0f) ? -1.0f : ((sum < 0.0f) ? 1.0f : 0.0f);
    float a = fsigm(sg * u);
    float b = fsigm(sg * l);
    return fmaxf(fabsf(a - b), 1e-9f);
}

// LDS param map: [0..32]=softplus(m), [33..44]=tanh(f), [45..57]=b, 58=sc, 59=inv
__global__ __launch_bounds__(256, 4) void eb_fused(
    const float* __restrict__ x, const float* __restrict__ nz,
    const float* __restrict__ s,
    const float* __restrict__ m0_, const float* __restrict__ b0_, const float* __restrict__ f0_,
    const float* __restrict__ m1_, const float* __restrict__ b1_, const float* __restrict__ f1_,
    const float* __restrict__ m2_, const float* __restrict__ b2_, const float* __restrict__ f2_,
    const float* __restrict__ m3_, const float* __restrict__ b3_, const float* __restrict__ f3_,
    const float* __restrict__ m4_, const float* __restrict__ b4_,
    float* __restrict__ out, int n)
{
    __shared__ float P[64];
    __shared__ float tab[NT];

    const int t = threadIdx.x;

    // ---- phase 0: parameter transform (one scalar per lane) ----
    if (t < 33) {
        const float* src = (t < 3)  ? (m0_ + t)
                         : (t < 12) ? (m1_ + (t - 3))
                         : (t < 21) ? (m2_ + (t - 12))
                         : (t < 30) ? (m3_ + (t - 21))
                                    : (m4_ + (t - 30));
        P[t] = fsoftplus(*src);
    } else if (t < 45) {
        const int k = t - 33;
        const float* src = (k < 3) ? (f0_ + k)
                         : (k < 6) ? (f1_ + (k - 3))
                         : (k < 9) ? (f2_ + (k - 6))
                                   : (f3_ + (k - 9));
        P[t] = ftanh(*src);
    } else if (t < 58) {
        const int k = t - 45;
        const float* src = (k < 3)  ? (b0_ + k)
                         : (k < 6)  ? (b1_ + (k - 3))
                         : (k < 9)  ? (b2_ + (k - 6))
                         : (k < 12) ? (b3_ + (k - 9))
                                    : b4_;
        P[t] = *src;
    } else if (t == 58) {
        float sc = fmaxf(s[0], 1e-4f);
        P[58] = sc;
        P[59] = 1.0f / sc;
    }
    __syncthreads();

    // ---- phase 1: tabulate F at this lane's node ----
    {
        EBP p;
#pragma unroll
        for (int i = 0; i < 3; i++) p.m0[i] = P[i];
#pragma unroll
        for (int i = 0; i < 9; i++) p.m1[i] = P[3 + i];
#pragma unroll
        for (int i = 0; i < 9; i++) p.m2[i] = P[12 + i];
#pragma unroll
        for (int i = 0; i < 9; i++) p.m3[i] = P[21 + i];
#pragma unroll
        for (int i = 0; i < 3; i++) p.m4[i] = P[30 + i];
#pragma unroll
        for (int i = 0; i < 3; i++) { p.t0[i] = P[33 + i]; p.t1[i] = P[36 + i]; p.t2[i] = P[39 + i]; p.t3[i] = P[42 + i]; }
#pragma unroll
        for (int i = 0; i < 3; i++) { p.b0[i] = P[45 + i]; p.b1[i] = P[48 + i]; p.b2[i] = P[51 + i]; p.b3[i] = P[54 + i]; }
        p.b4 = P[57];

        const float hstep = (THI - TLO) / (float)(NT - 1);
        tab[t] = eb_lik(p, TLO + (float)t * hstep);
    }
    __syncthreads();

    // ---- phase 2: memory-bound streaming pass ----
    const float sc   = P[58];
    const float inv  = P[59];
    const float invh = (float)(NT - 1) / (THI - TLO);
    const float qa   = inv * sc;
    const float ta   = inv * invh;
    const float tb   = -TLO * invh;
    const float tmax = (float)(NT - 1) - 1e-3f;   // floor() <= NT-2

    float* __restrict__ oq = out;
    float* __restrict__ ol = out + n;

    const int nv4 = n >> 2;                       // float4 count
    const int gid = blockIdx.x * blockDim.x + threadIdx.x;
    const int T   = gridDim.x * blockDim.x;
    const v4f* __restrict__ x4 = (const v4f*)x;
    const v4f* __restrict__ n4 = (const v4f*)nz;
    v4f* __restrict__ oq4 = (v4f*)oq;
    v4f* __restrict__ ol4 = (v4f*)ol;

    int base = 0;
    // main: 4 float4 per thread per pass, all loads independent & lane-coalesced.
    for (; base + 4 * T <= nv4; base += 4 * T) {
        v4f xv[4], nv[4];
#pragma unroll
        for (int k = 0; k < 4; k++) {
            const int idx = base + gid + k * T;
            xv[k] = x4[idx];
            nv[k] = n4[idx];
        }
#pragma unroll
        for (int k = 0; k < 4; k++) {
            const int idx = base + gid + k * T;
            v4f qv, lv;
#pragma unroll
            for (int j = 0; j < 4; j++) {
                qv[j] = fmaf(xv[k][j], qa, nv[k][j] * sc);
                float tt = fmaf(xv[k][j], ta, tb);
                tt = fminf(fmaxf(tt, 0.0f), tmax);
                float fi = floorf(tt);
                int ii = (int)fi;
                float f0 = tab[ii];
                float f1 = tab[ii + 1];
                lv[j] = fmaf(tt - fi, f1 - f0, f0);
            }
            oq4[idx] = qv;
            ol4[idx] = lv;
        }
    }
    // leftover float4s
    for (int i = base + gid; i < nv4; i += T) {
        v4f xa = x4[i], na = n4[i];
        v4f qv, lv;
#pragma unroll
        for (int j = 0; j < 4; j++) {
            qv[j] = fmaf(xa[j], qa, na[j] * sc);
            float tt = fmaf(xa[j], ta, tb);
            tt = fminf(fmaxf(tt, 0.0f), tmax);
            float fi = floorf(tt);
            int ii = (int)fi;
            float f0 = tab[ii];
            float f1 = tab[ii + 1];
            lv[j] = fmaf(tt - fi, f1 - f0, f0);
        }
        oq4[i] = qv;
        ol4[i] = lv;
    }
    // scalar tail (n % 4) — not hit for N=8388608
    for (int i = (nv4 << 2) + gid; i < n; i += T) {
        float xvs = x[i];
        oq[i] = fmaf(xvs, qa, nz[i] * sc);
        float tt = fmaf(xvs, ta, tb);
        tt = fminf(fmaxf(tt, 0.0f), tmax);
        float fi = floorf(tt);
        int ii = (int)fi;
        float f0 = tab[ii];
        float f1 = tab[ii + 1];
        ol[i] = fmaf(tt - fi, f1 - f0, f0);
    }
}

extern "C" void kernel_launch(void* const* d_in, const int* in_sizes, int n_in,
                              void* d_out, int out_size, void* d_ws, size_t ws_size,
                              hipStream_t stream) {
    const float* x  = (const float*)d_in[0];
    const float* nz = (const float*)d_in[1];
    const float* s  = (const float*)d_in[2];
    const float* m0 = (const float*)d_in[3];
    const float* b0 = (const float*)d_in[4];
    const float* f0 = (const float*)d_in[5];
    const float* m1 = (const float*)d_in[6];
    const float* b1 = (const float*)d_in[7];
    const float* f1 = (const float*)d_in[8];
    const float* m2 = (const float*)d_in[9];
    const float* b2 = (const float*)d_in[10];
    const float* f2 = (const float*)d_in[11];
    const float* m3 = (const float*)d_in[12];
    const float* b3 = (const float*)d_in[13];
    const float* f3 = (const float*)d_in[14];
    const float* m4 = (const float*)d_in[15];
    const float* b4 = (const float*)d_in[16];
    const int n = in_sizes[0];

    // 2048 blocks x 256: 8 blocks/CU (32 waves/CU); at N=2^23 the main pass
    // covers the whole array in exactly one iteration (2048*256*16 == N).
    eb_fused<<<2048, 256, 0, stream>>>(x, nz, s,
                                       m0, b0, f0, m1, b1, f1,
                                       m2, b2, f2, m3, b3, f3,
                                       m4, b4,
                                       (float*)d_out, n);
}